// Round 3
// baseline (475.978 us; speedup 1.0000x reference)
//
#include <hip/hip_runtime.h>

typedef __bf16 bf16x8 __attribute__((ext_vector_type(8)));
typedef __bf16 bf16x4 __attribute__((ext_vector_type(4)));
typedef float  f32x4  __attribute__((ext_vector_type(4)));

#define ALPHA 0.08838834764831843f
#define INV_N 0.0009765625f   // 1/1024
#define HD    512             // H*D

// LDS layout (21632 B total):
//   smK : 8192 B  K-chunk [32 j][128 d] bf16, byte ^= (j&7)<<4  (XOR stays in 256B row)
//   smV : 8320 B  V-chunk grouped [g=j>>3][128 d][j&7] bf16, 2080 B/group (PV B-frags)
//   smP : 5120 B  per-wave P [16 i][32 j] bf16, row stride 80 B (no XOR; 16B-aligned reads)
__global__ __launch_bounds__(256)
void hstu_attn_fwd(const float* __restrict__ Q, const float* __restrict__ K,
                   const float* __restrict__ V,
                   const int* __restrict__ offs,
                   const int* __restrict__ ntgt,
                   float* __restrict__ Out)
{
    __shared__ __align__(16) char smem[21632];
    char* smK = smem;
    char* smV = smem + 8192;
    char* smP = smem + 16512;

    const int b  = blockIdx.z;
    const int h  = blockIdx.y;
    const int r0 = blockIdx.x << 6;          // 64 rows per block

    const int s0 = offs[b];
    const int L  = offs[b + 1] - s0;
    if (r0 >= L) return;                      // block-uniform
    const int cap = L - ntgt[b];

    const int tid  = threadIdx.x;
    const int w    = tid >> 6;
    const int lane = tid & 63;
    const int l15  = lane & 15;
    const int g8   = lane >> 4;

    const int wr0 = r0 + (w << 4);           // this wave's first row
    int wave_jmax;
    if (wr0 >= L)            wave_jmax = 0;            // no valid rows
    else if (wr0 + 16 > cap) wave_jmax = L;            // contains target rows -> full
    else                     wave_jmax = wr0 + 16;     // causal

    const int jmax = (r0 + 64 > cap) ? L : (r0 + 64);  // block-uniform chunk bound
    const int nch  = (jmax + 31) >> 5;

    const f32x4 fzero = {0.f, 0.f, 0.f, 0.f};

    // ---- Q A-fragments (rows wr0..wr0+15): lane row = l15, k = g8*8+e per 32-d chunk ----
    bf16x8 qa[4];
    {
        const int qr = wr0 + l15;
        if (qr < L) {
            const float* qp = Q + (size_t)(s0 + qr) * HD + h * 128 + g8 * 8;
#pragma unroll
            for (int kc = 0; kc < 4; ++kc) {
                f32x4 x0 = *(const f32x4*)(qp + kc * 32);
                f32x4 x1 = *(const f32x4*)(qp + kc * 32 + 4);
                bf16x8 a;
#pragma unroll
                for (int e = 0; e < 4; ++e) { a[e] = (__bf16)x0[e]; a[e + 4] = (__bf16)x1[e]; }
                qa[kc] = a;
            }
        } else {
#pragma unroll
            for (int kc = 0; kc < 4; ++kc)
#pragma unroll
                for (int e = 0; e < 8; ++e) qa[kc][e] = (__bf16)0.0f;
        }
    }

    f32x4 oacc[8];
#pragma unroll
    for (int i = 0; i < 8; ++i) oacc[i] = fzero;

    const int gi0 = wr0 + (g8 << 2);          // C-layout row base for this lane
    const int pbase = w * 1280;               // per-wave P tile (16 rows x 80 B)

    for (int c = 0; c < nch; ++c) {
        const int j0 = c << 5;

        // ---- stage K chunk: coalesced float4, cvt bf16, swizzled LDS write ----
#pragma unroll
        for (int s = 0; s < 4; ++s) {
            const int flat = s * 1024 + tid * 4;
            const int j = flat >> 7, d = flat & 127;
            const int gj = j0 + j;
            f32x4 x = fzero;
            if (gj < L) x = *(const f32x4*)(K + (size_t)(s0 + gj) * HD + h * 128 + d);
            bf16x4 kb;
#pragma unroll
            for (int e = 0; e < 4; ++e) kb[e] = (__bf16)x[e];
            const int byt = (j * 256 + d * 2) ^ ((j & 7) << 4);
            *(bf16x4*)(smK + byt) = kb;
        }
        // ---- stage V chunk: 4 j-rows per thread -> contiguous [g][d][jj] write ----
#pragma unroll
        for (int s = 0; s < 4; ++s) {
            const int jb = ((tid >> 7) << 2) + s * 8;   // rows jb..jb+3
            const int d  = tid & 127;
            bf16x4 vb;
#pragma unroll
            for (int r = 0; r < 4; ++r) {
                const int gj = j0 + jb + r;
                float val = 0.f;
                if (gj < L) val = V[(size_t)(s0 + gj) * HD + h * 128 + d];
                vb[r] = (__bf16)val;
            }
            *(bf16x4*)(smV + (jb >> 3) * 2080 + d * 16 + (jb & 7) * 2) = vb;
        }
        __syncthreads();

        if (j0 < wave_jmax) {
            // ---- S = Q K^T over two 16-wide j tiles ----
#pragma unroll
            for (int jt = 0; jt < 2; ++jt) {
                f32x4 sacc = fzero;
                const int jl = (jt << 4) + l15;
#pragma unroll
                for (int kc = 0; kc < 4; ++kc) {
                    const int d = kc * 32 + g8 * 8;
                    const int byt = (jl * 256 + d * 2) ^ ((jl & 7) << 4);
                    bf16x8 kb = *(const bf16x8*)(smK + byt);
                    sacc = __builtin_amdgcn_mfma_f32_16x16x32_bf16(qa[kc], kb, sacc, 0, 0, 0);
                }
                // ---- silu + mask -> P (bf16, per-wave LDS tile, 80 B row stride) ----
                const int gj = j0 + (jt << 4) + l15;
#pragma unroll
                for (int r = 0; r < 4; ++r) {
                    const int gir = gi0 + r;
                    const float x = sacc[r] * ALPHA;
                    float p = x / (1.f + __expf(-x)) * INV_N;
                    const bool valid = (gj < L) && ((gj <= gir) || (gir >= cap));
                    p = valid ? p : 0.f;
                    const int iw = (g8 << 2) + r;
                    *(__bf16*)(smP + pbase + iw * 80 + ((jt << 4) + l15) * 2) = (__bf16)p;
                }
            }
            // same-wave DS ordering; fence keeps compiler from reordering
            asm volatile("s_waitcnt lgkmcnt(0)" ::: "memory");
            const bf16x8 pa = *(const bf16x8*)(smP + pbase + l15 * 80 + g8 * 16);
            // ---- O += P V ----
#pragma unroll
            for (int dt = 0; dt < 8; ++dt) {
                bf16x8 vbf = *(const bf16x8*)(smV + g8 * 2080 + ((dt << 4) + l15) * 16);
                oacc[dt] = __builtin_amdgcn_mfma_f32_16x16x32_bf16(pa, vbf, oacc[dt], 0, 0, 0);
            }
        }
        __syncthreads();
    }

    // ---- write O (f32): row gi0+r, col dt*16+l15 ----
#pragma unroll
    for (int r = 0; r < 4; ++r) {
        const int gir = gi0 + r;
        if (gir < L) {
            float* op = Out + (size_t)(s0 + gir) * HD + h * 128 + l15;
#pragma unroll
            for (int dt = 0; dt < 8; ++dt) op[dt << 4] = oacc[dt][r];
        }
    }
}

extern "C" void kernel_launch(void* const* d_in, const int* in_sizes, int n_in,
                              void* d_out, int out_size, void* d_ws, size_t ws_size,
                              hipStream_t stream) {
    (void)in_sizes; (void)n_in; (void)d_ws; (void)ws_size; (void)out_size;
    const float* q = (const float*)d_in[0];
    const float* k = (const float*)d_in[1];
    const float* v = (const float*)d_in[2];
    const int* offs = (const int*)d_in[3];
    const int* ntgt = (const int*)d_in[4];
    float* out = (float*)d_out;
    dim3 grid(16, 4, 32), block(256, 1, 1);
    hipLaunchKernelGGL(hstu_attn_fwd, grid, block, 0, stream, q, k, v, offs, ntgt, out);
}

// Round 4
// 120.916 us; speedup vs baseline: 3.9364x; 3.9364x over previous
//
#include <hip/hip_runtime.h>

typedef __bf16 bf16x8 __attribute__((ext_vector_type(8)));
typedef float  f32x4  __attribute__((ext_vector_type(4)));

#define ALPHA 0.08838834764831843f
#define INV_N 0.0009765625f   // 1/1024
#define HD    512             // H*D

// 8 waves (512 thr), row-tile 128 (wave owns 16 rows), KV chunk 64.
// LDS (53504 B): smK 16384 [64 j][128 d] bf16, byt ^= (j&7)<<4
//                smV 16640 grouped [g=j>>3][128 d][j&7] bf16, 2080 B/group
//                smP 20480 per-wave 2x(16 i x 32 j) bf16, 80 B row stride
__global__ __launch_bounds__(512)
void hstu_attn_fwd(const float* __restrict__ Q, const float* __restrict__ K,
                   const float* __restrict__ V,
                   const int* __restrict__ offs,
                   const int* __restrict__ ntgt,
                   float* __restrict__ Out)
{
    __shared__ __align__(16) char smem[53504];
    char* smK = smem;
    char* smV = smem + 16384;
    char* smP = smem + 33024;

    // XCD-grouped decode: all 8 row-tiles of a (b,h) share bx%8 -> same XCD
    const int bx  = blockIdx.x;
    const int xcd = bx & 7;
    const int q5  = bx >> 3;
    const int t   = q5 & 7;
    const int gq  = q5 >> 3;            // 0..15
    const int g   = gq * 8 + xcd;       // 0..127 (b,h) group
    const int b   = g >> 2;
    const int h   = g & 3;
    const int r0  = t << 7;

    const int s0 = offs[b];
    const int L  = offs[b + 1] - s0;
    if (r0 >= L) return;
    const int cap = L - ntgt[b];

    const int tid = threadIdx.x;
    const int w = tid >> 6, lane = tid & 63, l15 = lane & 15, g8 = lane >> 4;

    const int wr0 = r0 + (w << 4);
    int wave_jmax;
    if (wr0 >= L)            wave_jmax = 0;
    else if (wr0 + 16 > cap) wave_jmax = L;
    else                     wave_jmax = wr0 + 16;

    const int jmax = (r0 + 128 > cap) ? L : (r0 + 128);
    const int nch  = (jmax + 63) >> 6;

    const float* Kb = K + (size_t)s0 * HD + h * 128;
    const float* Vb = V + (size_t)s0 * HD + h * 128;

    // ---- Q A-fragments (clamped row; garbage rows masked at P / not stored) ----
    bf16x8 qa[4];
    {
        int qr = wr0 + l15; if (qr > L - 1) qr = L - 1;
        const float* qp = Q + (size_t)(s0 + qr) * HD + h * 128 + g8 * 8;
#pragma unroll
        for (int kc = 0; kc < 4; ++kc) {
            f32x4 x0 = *(const f32x4*)(qp + kc * 32);
            f32x4 x1 = *(const f32x4*)(qp + kc * 32 + 4);
            bf16x8 a;
#pragma unroll
            for (int e = 0; e < 4; ++e) { a[e] = (__bf16)x0[e]; a[e + 4] = (__bf16)x1[e]; }
            qa[kc] = a;
        }
    }

    f32x4 oacc[8];
#pragma unroll
    for (int i = 0; i < 8; ++i) oacc[i] = f32x4{0.f, 0.f, 0.f, 0.f};

    const int gi0   = wr0 + (g8 << 2);
    const int pbase = w * 2560;

    // staging decode (per-thread constants)
    const int kj0 = tid >> 4, kd8 = tid & 15;   // K: 16B unit (8 bf16 along d); +32 rows per s
    const int vg0 = tid >> 7, vd  = tid & 127;  // V: j-group gg = vg0+4s, column d

    f32x4 kreg[4];
    float vreg[16];

    // ---- prologue: prefetch chunk 0 into regs ----
#pragma unroll
    for (int s = 0; s < 2; ++s) {
        int j = kj0 + s * 32; if (j > L - 1) j = L - 1;
        const float* p = Kb + (size_t)j * HD + kd8 * 8;
        kreg[s * 2]     = *(const f32x4*)p;
        kreg[s * 2 + 1] = *(const f32x4*)(p + 4);
    }
#pragma unroll
    for (int s = 0; s < 2; ++s) {
        const int gg = vg0 + s * 4;
#pragma unroll
        for (int e = 0; e < 8; ++e) {
            int j = gg * 8 + e; if (j > L - 1) j = L - 1;
            vreg[s * 8 + e] = Vb[(size_t)j * HD + vd];
        }
    }

    for (int c = 0; c < nch; ++c) {
        const int j0 = c << 6;

        // ---- stage regs -> LDS (bf16) ----
#pragma unroll
        for (int s = 0; s < 2; ++s) {
            const int j = kj0 + s * 32;
            bf16x8 kb;
#pragma unroll
            for (int e = 0; e < 4; ++e) { kb[e] = (__bf16)kreg[s*2][e]; kb[e+4] = (__bf16)kreg[s*2+1][e]; }
            *(bf16x8*)(smK + ((j * 256 + kd8 * 16) ^ ((j & 7) << 4))) = kb;
        }
#pragma unroll
        for (int s = 0; s < 2; ++s) {
            const int gg = vg0 + s * 4;
            bf16x8 vbw;
#pragma unroll
            for (int e = 0; e < 8; ++e) vbw[e] = (__bf16)vreg[s * 8 + e];
            *(bf16x8*)(smV + gg * 2080 + vd * 16) = vbw;
        }
        __syncthreads();

        // ---- prefetch chunk c+1 (overlaps with compute below) ----
        if (c + 1 < nch) {
            const int jn = j0 + 64;
#pragma unroll
            for (int s = 0; s < 2; ++s) {
                int j = jn + kj0 + s * 32; if (j > L - 1) j = L - 1;
                const float* p = Kb + (size_t)j * HD + kd8 * 8;
                kreg[s * 2]     = *(const f32x4*)p;
                kreg[s * 2 + 1] = *(const f32x4*)(p + 4);
            }
#pragma unroll
            for (int s = 0; s < 2; ++s) {
                const int gg = vg0 + s * 4;
#pragma unroll
                for (int e = 0; e < 8; ++e) {
                    int j = jn + gg * 8 + e; if (j > L - 1) j = L - 1;
                    vreg[s * 8 + e] = Vb[(size_t)j * HD + vd];
                }
            }
        }

        if (j0 < wave_jmax) {
            // ---- S = Q K^T over four 16-wide j tiles ----
#pragma unroll
            for (int jt = 0; jt < 4; ++jt) {
                f32x4 sacc = f32x4{0.f, 0.f, 0.f, 0.f};
                const int jl = (jt << 4) + l15;
#pragma unroll
                for (int kc = 0; kc < 4; ++kc) {
                    const int byt = (jl * 256 + (kc * 32 + g8 * 8) * 2) ^ ((jl & 7) << 4);
                    bf16x8 kb = *(const bf16x8*)(smK + byt);
                    sacc = __builtin_amdgcn_mfma_f32_16x16x32_bf16(qa[kc], kb, sacc, 0, 0, 0);
                }
                const int gj = j0 + jl;
#pragma unroll
                for (int r = 0; r < 4; ++r) {
                    const int gir = gi0 + r;
                    const float x = sacc[r] * ALPHA;
                    float p = x / (1.f + __expf(-x)) * INV_N;
                    const bool valid = (gj < L) && ((gj <= gir) || (gir >= cap));
                    p = valid ? p : 0.f;
                    const int iw = (g8 << 2) + r;
                    *(__bf16*)(smP + pbase + (jt >> 1) * 1280 + iw * 80 +
                               ((((jt & 1) << 4) + l15) << 1)) = (__bf16)p;
                }
            }
            asm volatile("s_waitcnt lgkmcnt(0)" ::: "memory");
            // ---- O += P V (two 32-k halves) ----
#pragma unroll
            for (int kk = 0; kk < 2; ++kk) {
                const bf16x8 pa = *(const bf16x8*)(smP + pbase + kk * 1280 + l15 * 80 + g8 * 16);
#pragma unroll
                for (int dt = 0; dt < 8; ++dt) {
                    bf16x8 vb = *(const bf16x8*)(smV + (kk * 4 + g8) * 2080 + ((dt << 4) + l15) * 16);
                    oacc[dt] = __builtin_amdgcn_mfma_f32_16x16x32_bf16(pa, vb, oacc[dt], 0, 0, 0);
                }
            }
        }
        __syncthreads();
    }

    // ---- write O (f32): row gi0+r, col dt*16+l15 ----
#pragma unroll
    for (int r = 0; r < 4; ++r) {
        const int gir = gi0 + r;
        if (gir < L) {
            float* op = Out + (size_t)(s0 + gir) * HD + h * 128 + l15;
#pragma unroll
            for (int dt = 0; dt < 8; ++dt) op[dt << 4] = oacc[dt][r];
        }
    }
}

extern "C" void kernel_launch(void* const* d_in, const int* in_sizes, int n_in,
                              void* d_out, int out_size, void* d_ws, size_t ws_size,
                              hipStream_t stream) {
    (void)in_sizes; (void)n_in; (void)d_ws; (void)ws_size; (void)out_size;
    const float* q = (const float*)d_in[0];
    const float* k = (const float*)d_in[1];
    const float* v = (const float*)d_in[2];
    const int* offs = (const int*)d_in[3];
    const int* ntgt = (const int*)d_in[4];
    float* out = (float*)d_out;
    dim3 grid(1024, 1, 1), block(512, 1, 1);
    hipLaunchKernelGGL(hstu_attn_fwd, grid, block, 0, stream, q, k, v, offs, ntgt, out);
}

// Round 5
// 108.388 us; speedup vs baseline: 4.3914x; 1.1156x over previous
//
#include <hip/hip_runtime.h>

typedef __bf16 bf16x8 __attribute__((ext_vector_type(8)));
typedef float  f32x4  __attribute__((ext_vector_type(4)));

#define ALPHA 0.08838834764831843f
#define INV_N 0.0009765625f   // 1/1024
#define HD    512             // H*D

// 8 waves (512 thr). Diagonal-fold: block handles row-tiles {f, T-1-f} (128 rows
// each) sequentially -> per-block work ~const (2T+2 chunks). KV chunk 64.
// LDS (53504 B): smK 16384 [64 j][128 d] bf16, byt ^= (j&7)<<4
//                smV 16640 grouped [g=j>>3][128 d][j&7] bf16, 2080 B/group
//                smP 20480 per-wave 2x(16 i x 32 j) bf16, 80 B row stride
__global__ __launch_bounds__(512)
void hstu_attn_fwd(const float* __restrict__ Q, const float* __restrict__ K,
                   const float* __restrict__ V,
                   const int* __restrict__ offs,
                   const int* __restrict__ ntgt,
                   float* __restrict__ Out)
{
    __shared__ __align__(16) char smem[53504];
    char* smK = smem;
    char* smV = smem + 16384;
    char* smP = smem + 33024;

    // XCD-grouped decode: the 4 fold-blocks of a (b,h) share n&7 -> same XCD
    const int n   = blockIdx.x;
    const int xcd = n & 7;
    const int r5  = n >> 3;
    const int f   = r5 & 3;
    const int gq  = r5 >> 2;            // 0..15
    const int G   = gq * 8 + xcd;       // 0..127 (b,h)
    const int b   = G >> 2;
    const int h   = G & 3;

    const int s0 = offs[b];
    const int L  = offs[b + 1] - s0;
    const int T  = (L + 127) >> 7;
    const int t1 = f, t2 = T - 1 - f;
    if (t1 > t2) return;                 // idle fold
    const int cap = L - ntgt[b];

    const int tid = threadIdx.x;
    const int w = tid >> 6, lane = tid & 63, l15 = lane & 15, g8 = lane >> 4;

    const float* Kb = K + (size_t)s0 * HD + h * 128;
    const float* Vb = V + (size_t)s0 * HD + h * 128;

    // staging decode (per-thread constants)
    const int kj0 = tid >> 4, kd8 = tid & 15;   // K: 16B unit (8 bf16 along d); +32 rows per s
    const int vg0 = tid >> 7, vd  = tid & 127;  // V: j-group gg = vg0+4s, column d

    const int pbase = w * 2560;
    const int nph = (t1 == t2) ? 1 : 2;

#pragma unroll 1
    for (int ph = 0; ph < nph; ++ph) {
        const int r0  = (ph ? t2 : t1) << 7;
        const int wr0 = r0 + (w << 4);

        int wave_jmax;
        if (wr0 >= L)            wave_jmax = 0;
        else if (wr0 + 16 > cap) wave_jmax = L;
        else                     wave_jmax = wr0 + 16;

        const int jmax = (r0 + 128 > cap) ? L : (r0 + 128);
        const int nch  = (jmax + 63) >> 6;

        // ---- Q A-fragments (clamped row; invalid rows masked at P / not stored) ----
        bf16x8 qa[4];
        {
            int qr = wr0 + l15; if (qr > L - 1) qr = L - 1;
            const float* qp = Q + (size_t)(s0 + qr) * HD + h * 128 + g8 * 8;
#pragma unroll
            for (int kc = 0; kc < 4; ++kc) {
                f32x4 x0 = *(const f32x4*)(qp + kc * 32);
                f32x4 x1 = *(const f32x4*)(qp + kc * 32 + 4);
                bf16x8 a;
#pragma unroll
                for (int e = 0; e < 4; ++e) { a[e] = (__bf16)x0[e]; a[e + 4] = (__bf16)x1[e]; }
                qa[kc] = a;
            }
        }

        f32x4 oacc[8];
#pragma unroll
        for (int i = 0; i < 8; ++i) oacc[i] = f32x4{0.f, 0.f, 0.f, 0.f};

        const int gi0 = wr0 + (g8 << 2);

        f32x4 kreg[4];
        float vreg[16];

        // ---- prologue: prefetch chunk 0 into regs ----
#pragma unroll
        for (int s = 0; s < 2; ++s) {
            int j = kj0 + s * 32; if (j > L - 1) j = L - 1;
            const float* p = Kb + (size_t)j * HD + kd8 * 8;
            kreg[s * 2]     = *(const f32x4*)p;
            kreg[s * 2 + 1] = *(const f32x4*)(p + 4);
        }
#pragma unroll
        for (int s = 0; s < 2; ++s) {
            const int gg = vg0 + s * 4;
#pragma unroll
            for (int e = 0; e < 8; ++e) {
                int j = gg * 8 + e; if (j > L - 1) j = L - 1;
                vreg[s * 8 + e] = Vb[(size_t)j * HD + vd];
            }
        }

        for (int c = 0; c < nch; ++c) {
            const int j0 = c << 6;

            // ---- stage regs -> LDS (bf16) ----
#pragma unroll
            for (int s = 0; s < 2; ++s) {
                const int j = kj0 + s * 32;
                bf16x8 kb;
#pragma unroll
                for (int e = 0; e < 4; ++e) { kb[e] = (__bf16)kreg[s*2][e]; kb[e+4] = (__bf16)kreg[s*2+1][e]; }
                *(bf16x8*)(smK + ((j * 256 + kd8 * 16) ^ ((j & 7) << 4))) = kb;
            }
#pragma unroll
            for (int s = 0; s < 2; ++s) {
                const int gg = vg0 + s * 4;
                bf16x8 vbw;
#pragma unroll
                for (int e = 0; e < 8; ++e) vbw[e] = (__bf16)vreg[s * 8 + e];
                *(bf16x8*)(smV + gg * 2080 + vd * 16) = vbw;
            }
            __syncthreads();

            // ---- prefetch chunk c+1 (overlaps compute below) ----
            if (c + 1 < nch) {
                const int jn = j0 + 64;
#pragma unroll
                for (int s = 0; s < 2; ++s) {
                    int j = jn + kj0 + s * 32; if (j > L - 1) j = L - 1;
                    const float* p = Kb + (size_t)j * HD + kd8 * 8;
                    kreg[s * 2]     = *(const f32x4*)p;
                    kreg[s * 2 + 1] = *(const f32x4*)(p + 4);
                }
#pragma unroll
                for (int s = 0; s < 2; ++s) {
                    const int gg = vg0 + s * 4;
#pragma unroll
                    for (int e = 0; e < 8; ++e) {
                        int j = jn + gg * 8 + e; if (j > L - 1) j = L - 1;
                        vreg[s * 8 + e] = Vb[(size_t)j * HD + vd];
                    }
                }
            }

            if (j0 < wave_jmax) {
                // ---- S = Q K^T over four 16-wide j tiles ----
#pragma unroll
                for (int jt = 0; jt < 4; ++jt) {
                    f32x4 sacc = f32x4{0.f, 0.f, 0.f, 0.f};
                    const int jl = (jt << 4) + l15;
                    __builtin_amdgcn_s_setprio(1);
#pragma unroll
                    for (int kc = 0; kc < 4; ++kc) {
                        const int byt = (jl * 256 + (kc * 32 + g8 * 8) * 2) ^ ((jl & 7) << 4);
                        bf16x8 kb = *(const bf16x8*)(smK + byt);
                        sacc = __builtin_amdgcn_mfma_f32_16x16x32_bf16(qa[kc], kb, sacc, 0, 0, 0);
                    }
                    __builtin_amdgcn_s_setprio(0);
                    const int gj = j0 + jl;
#pragma unroll
                    for (int r = 0; r < 4; ++r) {
                        const int gir = gi0 + r;
                        const float x = sacc[r] * ALPHA;
                        float p = x * __builtin_amdgcn_rcpf(1.f + __expf(-x)) * INV_N;
                        const bool valid = (gj < L) && ((gj <= gir) || (gir >= cap));
                        p = valid ? p : 0.f;
                        const int iw = (g8 << 2) + r;
                        *(__bf16*)(smP + pbase + (jt >> 1) * 1280 + iw * 80 +
                                   ((((jt & 1) << 4) + l15) << 1)) = (__bf16)p;
                    }
                }
                asm volatile("s_waitcnt lgkmcnt(0)" ::: "memory");
                // ---- O += P V (two 32-k halves) ----
                __builtin_amdgcn_s_setprio(1);
#pragma unroll
                for (int kk = 0; kk < 2; ++kk) {
                    const bf16x8 pa = *(const bf16x8*)(smP + pbase + kk * 1280 + l15 * 80 + g8 * 16);
#pragma unroll
                    for (int dt = 0; dt < 8; ++dt) {
                        bf16x8 vb = *(const bf16x8*)(smV + (kk * 4 + g8) * 2080 + ((dt << 4) + l15) * 16);
                        oacc[dt] = __builtin_amdgcn_mfma_f32_16x16x32_bf16(pa, vb, oacc[dt], 0, 0, 0);
                    }
                }
                __builtin_amdgcn_s_setprio(0);
            }
            __syncthreads();
        }

        // ---- write O (f32): row gi0+r, col dt*16+l15 ----
#pragma unroll
        for (int r = 0; r < 4; ++r) {
            const int gir = gi0 + r;
            if (gir < L) {
                float* op = Out + (size_t)(s0 + gir) * HD + h * 128 + l15;
#pragma unroll
                for (int dt = 0; dt < 8; ++dt) op[dt << 4] = oacc[dt][r];
            }
        }
    }
}

extern "C" void kernel_launch(void* const* d_in, const int* in_sizes, int n_in,
                              void* d_out, int out_size, void* d_ws, size_t ws_size,
                              hipStream_t stream) {
    (void)in_sizes; (void)n_in; (void)d_ws; (void)ws_size; (void)out_size;
    const float* q = (const float*)d_in[0];
    const float* k = (const float*)d_in[1];
    const float* v = (const float*)d_in[2];
    const int* offs = (const int*)d_in[3];
    const int* ntgt = (const int*)d_in[4];
    float* out = (float*)d_out;
    dim3 grid(512, 1, 1), block(512, 1, 1);
    hipLaunchKernelGGL(hstu_attn_fwd, grid, block, 0, stream, q, k, v, offs, ntgt, out);
}

// Round 6
// 107.696 us; speedup vs baseline: 4.4196x; 1.0064x over previous
//
#include <hip/hip_runtime.h>

typedef __bf16 bf16x8 __attribute__((ext_vector_type(8)));
typedef float  f32x4  __attribute__((ext_vector_type(4)));

#define ALPHA 0.08838834764831843f
#define INV_N 0.0009765625f   // 1/1024
#define HD    512             // H*D

__device__ __forceinline__ unsigned int cvt_pk_bf16(float lo, float hi) {
    unsigned int r;
    asm("v_cvt_pk_bf16_f32 %0, %1, %2" : "=v"(r) : "v"(lo), "v"(hi));
    return r;
}

union PA8 { unsigned int u[4]; bf16x8 v; };

// 8 waves (512 thr), diagonal-fold {f, T-1-f}, 128 rows/phase, KV chunk 64.
// Ping-pong LDS: 2 bufs x (K 16384 [64j][128d] bf16 XOR-swz + V 16384 grouped
// [g=j>>3][128 d][j&7]) = 65536 B. One barrier per chunk. P never touches LDS:
// swapped QK^T (S^T in regs) -> cvt_pk -> ds_bpermute exchange -> PV A-frags.
__global__ __launch_bounds__(512)
void hstu_attn_fwd(const float* __restrict__ Q, const float* __restrict__ K,
                   const float* __restrict__ V,
                   const int* __restrict__ offs,
                   const int* __restrict__ ntgt,
                   float* __restrict__ Out)
{
    __shared__ __align__(16) char smem[65536];

    // XCD-grouped decode: the 4 fold-blocks of a (b,h) share n&7 -> same XCD
    const int n   = blockIdx.x;
    const int xcd = n & 7;
    const int r5  = n >> 3;
    const int f   = r5 & 3;
    const int gq  = r5 >> 2;
    const int G   = gq * 8 + xcd;       // (b,h)
    const int b   = G >> 2;
    const int h   = G & 3;

    const int s0 = offs[b];
    const int L  = offs[b + 1] - s0;
    const int T  = (L + 127) >> 7;
    const int t1 = f, t2 = T - 1 - f;
    if (t1 > t2) return;
    const int cap = L - ntgt[b];

    const int tid = threadIdx.x;
    const int w = tid >> 6, lane = tid & 63, l15 = lane & 15, g8 = lane >> 4;

    const float* Kb = K + (size_t)s0 * HD + h * 128;
    const float* Vb = V + (size_t)s0 * HD + h * 128;

    // staging decode
    const int kj0 = tid >> 4, kd8 = tid & 15;   // K: row kj0(+32s), 16B unit kd8
    const int vg0 = tid >> 7, vd  = tid & 127;  // V: group vg0(+4s), column vd

    // bpermute addresses for the P exchange (bytes = lane*4)
    const int addrA = ((((g8 & 1) << 5) + l15) << 2);
    const int addrB = addrA + 64;

    const int nph = (t1 == t2) ? 1 : 2;

    auto load_chunk = [&](int j0c, f32x4* kreg, float* vreg) {
#pragma unroll
        for (int s = 0; s < 2; ++s) {
            int j = j0c + kj0 + s * 32; if (j > L - 1) j = L - 1;
            const float* p = Kb + (size_t)j * HD + kd8 * 8;
            kreg[s * 2]     = *(const f32x4*)p;
            kreg[s * 2 + 1] = *(const f32x4*)(p + 4);
        }
#pragma unroll
        for (int s = 0; s < 2; ++s) {
            const int gg = vg0 + s * 4;
#pragma unroll
            for (int e = 0; e < 8; ++e) {
                int j = j0c + gg * 8 + e; if (j > L - 1) j = L - 1;
                vreg[s * 8 + e] = Vb[(size_t)j * HD + vd];
            }
        }
    };
    auto write_buf = [&](int q, const f32x4* kreg, const float* vreg) {
        char* wK = smem + q * 32768;
        char* wV = wK + 16384;
#pragma unroll
        for (int s = 0; s < 2; ++s) {
            const int j = kj0 + s * 32;
            bf16x8 kb;
#pragma unroll
            for (int e = 0; e < 4; ++e) { kb[e] = (__bf16)kreg[s*2][e]; kb[e+4] = (__bf16)kreg[s*2+1][e]; }
            *(bf16x8*)(wK + ((j * 256 + kd8 * 16) ^ ((j & 7) << 4))) = kb;
        }
#pragma unroll
        for (int s = 0; s < 2; ++s) {
            bf16x8 vbw;
#pragma unroll
            for (int e = 0; e < 8; ++e) vbw[e] = (__bf16)vreg[s * 8 + e];
            *(bf16x8*)(wV + (vg0 + s * 4) * 2048 + vd * 16) = vbw;
        }
    };

#pragma unroll 1
    for (int ph = 0; ph < nph; ++ph) {
        const int r0  = (ph ? t2 : t1) << 7;
        const int wr0 = r0 + (w << 4);

        int wave_jmax;
        if (wr0 >= L)            wave_jmax = 0;
        else if (wr0 + 16 > cap) wave_jmax = L;
        else                     wave_jmax = wr0 + 16;

        const int jmax = (r0 + 128 > cap) ? L : (r0 + 128);
        const int nch  = (jmax + 63) >> 6;

        // ---- Q fragments: q = wr0 + l15 (B-operand of swapped QK^T) ----
        bf16x8 qa[4];
        {
            int qr = wr0 + l15; if (qr > L - 1) qr = L - 1;
            const float* qp = Q + (size_t)(s0 + qr) * HD + h * 128 + g8 * 8;
#pragma unroll
            for (int kc = 0; kc < 4; ++kc) {
                f32x4 x0 = *(const f32x4*)(qp + kc * 32);
                f32x4 x1 = *(const f32x4*)(qp + kc * 32 + 4);
                bf16x8 a;
#pragma unroll
                for (int e = 0; e < 4; ++e) { a[e] = (__bf16)x0[e]; a[e + 4] = (__bf16)x1[e]; }
                qa[kc] = a;
            }
        }

        f32x4 oacc[8];
#pragma unroll
        for (int i = 0; i < 8; ++i) oacc[i] = f32x4{0.f, 0.f, 0.f, 0.f};

        const int qrow  = wr0 + l15;         // this lane's q-row in S^T/P space
        const int orow0 = wr0 + (g8 << 2);   // output C-layout row base

        f32x4 kreg[4];
        float vreg[16];

        // prologue: chunk0 -> buf0; prefetch chunk1
        load_chunk(0, kreg, vreg);
        write_buf(0, kreg, vreg);
        if (nch > 1) load_chunk(64, kreg, vreg);
        __syncthreads();

        for (int c = 0; c < nch; ++c) {
            const int j0 = c << 6;
            const char* bK = smem + (c & 1) * 32768;
            const char* bV = bK + 16384;

            if (j0 < wave_jmax) {
                unsigned int pk[4][2];
                __builtin_amdgcn_s_setprio(1);
#pragma unroll
                for (int jt = 0; jt < 4; ++jt) {
                    f32x4 sacc = f32x4{0.f, 0.f, 0.f, 0.f};
                    const int jl = (jt << 4) + l15;
#pragma unroll
                    for (int kc = 0; kc < 4; ++kc) {
                        const int byt = (jl * 256 + (kc * 32 + g8 * 8) * 2) ^ ((jl & 7) << 4);
                        bf16x8 kb = *(const bf16x8*)(bK + byt);
                        sacc = __builtin_amdgcn_mfma_f32_16x16x32_bf16(kb, qa[kc], sacc, 0, 0, 0);
                    }
                    // silu + mask: kv = j0 + 16*jt + 4*g8 + r, q = qrow
#pragma unroll
                    for (int r = 0; r < 4; ++r) {
                        const int gj = j0 + (jt << 4) + (g8 << 2) + r;
                        const float x = sacc[r] * ALPHA;
                        float p = x * __builtin_amdgcn_rcpf(1.f + __expf(-x)) * INV_N;
                        const bool valid = (gj < L) && ((gj <= qrow) || (qrow >= cap));
                        sacc[r] = valid ? p : 0.f;
                    }
                    pk[jt][0] = cvt_pk_bf16(sacc[0], sacc[1]);
                    pk[jt][1] = cvt_pk_bf16(sacc[2], sacc[3]);
                }
                // ---- in-register P exchange + PV ----
#pragma unroll
                for (int kk = 0; kk < 2; ++kk) {
                    PA8 pa;
#pragma unroll
                    for (int hp = 0; hp < 2; ++hp) {
                        const int ad = hp ? addrB : addrA;
#pragma unroll
                        for (int pr = 0; pr < 2; ++pr) {
                            const int ca = __builtin_amdgcn_ds_bpermute(ad, (int)pk[2*kk][pr]);
                            const int cb = __builtin_amdgcn_ds_bpermute(ad, (int)pk[2*kk+1][pr]);
                            pa.u[hp * 2 + pr] = (g8 < 2) ? (unsigned int)ca : (unsigned int)cb;
                        }
                    }
#pragma unroll
                    for (int dt = 0; dt < 8; ++dt) {
                        bf16x8 vb = *(const bf16x8*)(bV + (kk * 4 + g8) * 2048 + ((dt << 4) + l15) * 16);
                        oacc[dt] = __builtin_amdgcn_mfma_f32_16x16x32_bf16(pa.v, vb, oacc[dt], 0, 0, 0);
                    }
                }
                __builtin_amdgcn_s_setprio(0);
            }

            if (c + 1 < nch) write_buf((c + 1) & 1, kreg, vreg);
            if (c + 2 < nch) load_chunk((c + 2) << 6, kreg, vreg);
            __syncthreads();
        }

        // ---- write O (f32): row orow0+r, col dt*16+l15 ----
#pragma unroll
        for (int r = 0; r < 4; ++r) {
            const int gir = orow0 + r;
            if (gir < L) {
                float* op = Out + (size_t)(s0 + gir) * HD + h * 128 + l15;
#pragma unroll
                for (int dt = 0; dt < 8; ++dt) op[dt << 4] = oacc[dt][r];
            }
        }
    }
}

extern "C" void kernel_launch(void* const* d_in, const int* in_sizes, int n_in,
                              void* d_out, int out_size, void* d_ws, size_t ws_size,
                              hipStream_t stream) {
    (void)in_sizes; (void)n_in; (void)d_ws; (void)ws_size; (void)out_size;
    const float* q = (const float*)d_in[0];
    const float* k = (const float*)d_in[1];
    const float* v = (const float*)d_in[2];
    const int* offs = (const int*)d_in[3];
    const int* ntgt = (const int*)d_in[4];
    float* out = (float*)d_out;
    dim3 grid(512, 1, 1), block(512, 1, 1);
    hipLaunchKernelGGL(hstu_attn_fwd, grid, block, 0, stream, q, k, v, offs, ntgt, out);
}

// Round 7
// 94.487 us; speedup vs baseline: 5.0375x; 1.1398x over previous
//
#include <hip/hip_runtime.h>

typedef __bf16 bf16x8 __attribute__((ext_vector_type(8)));
typedef float  f32x4  __attribute__((ext_vector_type(4)));

#define ALPHA 0.08838834764831843f
#define INV_N 0.0009765625f   // 1/1024
#define HD    512             // H*D
#define NITEMS 1024           // 8 tt-levels x 128 (b,h) groups

__device__ __forceinline__ unsigned int cvt_pk_bf16(float lo, float hi) {
    unsigned int r;
    asm("v_cvt_pk_bf16_f32 %0, %1, %2" : "=v"(r) : "v"(lo), "v"(hi));
    return r;
}

union PA8 { unsigned int u[4]; bf16x8 v; };

// Persistent blocks (512 = 2/CU), dynamic LPT queue over 128-row tile items.
// Item it: tt = it>>7 (big tiles first), G = it&127 -> (b,h); t = T-1-tt.
// Per item: KV chunk 64, ping-pong LDS (2 x 32KB), 1 barrier/chunk,
// reg-prefetch 2 chunks ahead, swapped QK^T -> in-register P via bpermute.
__global__ __launch_bounds__(512)
void hstu_attn_fwd(const float* __restrict__ Q, const float* __restrict__ K,
                   const float* __restrict__ V,
                   const int* __restrict__ offs,
                   const int* __restrict__ ntgt,
                   float* __restrict__ Out,
                   unsigned int* __restrict__ ctr)
{
    __shared__ __align__(16) char smem[65536];
    __shared__ int s_item;

    const int tid = threadIdx.x;
    const int w = tid >> 6, lane = tid & 63, l15 = lane & 15, g8 = lane >> 4;

    // staging decode
    const int kj0 = tid >> 4, kd8 = tid & 15;   // K: row kj0(+32s), 16B unit kd8
    const int vg0 = tid >> 7, vd  = tid & 127;  // V: group vg0(+4s), column vd

    // bpermute addresses for the P exchange (bytes = lane*4)
    const int addrA = ((((g8 & 1) << 5) + l15) << 2);
    const int addrB = addrA + 64;

    for (;;) {
        __syncthreads();
        if (tid == 0) s_item = (int)atomicAdd(ctr, 1u);
        __syncthreads();
        const int it = s_item;
        if (it >= NITEMS) break;

        const int tt = it >> 7;
        const int G  = it & 127;
        const int b  = G >> 2;
        const int h  = G & 3;

        const int s0 = offs[b];
        const int L  = offs[b + 1] - s0;
        const int T  = (L + 127) >> 7;
        const int t  = T - 1 - tt;
        if (t < 0) continue;
        const int cap = L - ntgt[b];

        const float* Kb = K + (size_t)s0 * HD + h * 128;
        const float* Vb = V + (size_t)s0 * HD + h * 128;

        const int r0  = t << 7;
        const int wr0 = r0 + (w << 4);

        int wave_jmax;
        if (wr0 >= L)            wave_jmax = 0;
        else if (wr0 + 16 > cap) wave_jmax = L;
        else                     wave_jmax = wr0 + 16;

        const int jmax = (r0 + 128 > cap) ? L : (r0 + 128);
        const int nch  = (jmax + 63) >> 6;

        // ---- Q fragments: q = wr0 + l15 (B-operand of swapped QK^T) ----
        bf16x8 qa[4];
        {
            int qr = wr0 + l15; if (qr > L - 1) qr = L - 1;
            const float* qp = Q + (size_t)(s0 + qr) * HD + h * 128 + g8 * 8;
#pragma unroll
            for (int kc = 0; kc < 4; ++kc) {
                f32x4 x0 = *(const f32x4*)(qp + kc * 32);
                f32x4 x1 = *(const f32x4*)(qp + kc * 32 + 4);
                bf16x8 a;
#pragma unroll
                for (int e = 0; e < 4; ++e) { a[e] = (__bf16)x0[e]; a[e + 4] = (__bf16)x1[e]; }
                qa[kc] = a;
            }
        }

        f32x4 oacc[8];
#pragma unroll
        for (int i = 0; i < 8; ++i) oacc[i] = f32x4{0.f, 0.f, 0.f, 0.f};

        const int qrow  = wr0 + l15;         // this lane's q-row in S^T/P space
        const int orow0 = wr0 + (g8 << 2);   // output C-layout row base

        f32x4 kreg[4];
        float vreg[16];

        auto load_chunk = [&](int j0c) {
#pragma unroll
            for (int s = 0; s < 2; ++s) {
                int j = j0c + kj0 + s * 32; if (j > L - 1) j = L - 1;
                const float* p = Kb + (size_t)j * HD + kd8 * 8;
                kreg[s * 2]     = *(const f32x4*)p;
                kreg[s * 2 + 1] = *(const f32x4*)(p + 4);
            }
#pragma unroll
            for (int s = 0; s < 2; ++s) {
                const int gg = vg0 + s * 4;
#pragma unroll
                for (int e = 0; e < 8; ++e) {
                    int j = j0c + gg * 8 + e; if (j > L - 1) j = L - 1;
                    vreg[s * 8 + e] = Vb[(size_t)j * HD + vd];
                }
            }
        };
        auto write_buf = [&](int p) {
            char* wK = smem + p * 32768;
            char* wV = wK + 16384;
#pragma unroll
            for (int s = 0; s < 2; ++s) {
                const int j = kj0 + s * 32;
                bf16x8 kb;
#pragma unroll
                for (int e = 0; e < 4; ++e) { kb[e] = (__bf16)kreg[s*2][e]; kb[e+4] = (__bf16)kreg[s*2+1][e]; }
                *(bf16x8*)(wK + ((j * 256 + kd8 * 16) ^ ((j & 7) << 4))) = kb;
            }
#pragma unroll
            for (int s = 0; s < 2; ++s) {
                bf16x8 vbw;
#pragma unroll
                for (int e = 0; e < 8; ++e) vbw[e] = (__bf16)vreg[s * 8 + e];
                *(bf16x8*)(wV + (vg0 + s * 4) * 2048 + vd * 16) = vbw;
            }
        };

        // prologue: chunk0 -> buf0; prefetch chunk1
        load_chunk(0);
        write_buf(0);
        if (nch > 1) load_chunk(64);
        __syncthreads();

        for (int c = 0; c < nch; ++c) {
            const int j0 = c << 6;
            const char* bK = smem + (c & 1) * 32768;
            const char* bV = bK + 16384;

            if (j0 < wave_jmax) {
                unsigned int pk[4][2];
                __builtin_amdgcn_s_setprio(1);
#pragma unroll
                for (int jt = 0; jt < 4; ++jt) {
                    f32x4 sacc = f32x4{0.f, 0.f, 0.f, 0.f};
                    const int jl = (jt << 4) + l15;
#pragma unroll
                    for (int kc = 0; kc < 4; ++kc) {
                        const int byt = (jl * 256 + (kc * 32 + g8 * 8) * 2) ^ ((jl & 7) << 4);
                        bf16x8 kb = *(const bf16x8*)(bK + byt);
                        sacc = __builtin_amdgcn_mfma_f32_16x16x32_bf16(kb, qa[kc], sacc, 0, 0, 0);
                    }
                    // silu + mask: kv = j0 + 16*jt + 4*g8 + r, q = qrow
#pragma unroll
                    for (int r = 0; r < 4; ++r) {
                        const int gj = j0 + (jt << 4) + (g8 << 2) + r;
                        const float x = sacc[r] * ALPHA;
                        float p = x * __builtin_amdgcn_rcpf(1.f + __expf(-x)) * INV_N;
                        const bool valid = (gj < L) && ((gj <= qrow) || (qrow >= cap));
                        sacc[r] = valid ? p : 0.f;
                    }
                    pk[jt][0] = cvt_pk_bf16(sacc[0], sacc[1]);
                    pk[jt][1] = cvt_pk_bf16(sacc[2], sacc[3]);
                }
                // ---- in-register P exchange + PV ----
#pragma unroll
                for (int kk = 0; kk < 2; ++kk) {
                    PA8 pa;
#pragma unroll
                    for (int hp = 0; hp < 2; ++hp) {
                        const int ad = hp ? addrB : addrA;
#pragma unroll
                        for (int pr = 0; pr < 2; ++pr) {
                            const int ca = __builtin_amdgcn_ds_bpermute(ad, (int)pk[2*kk][pr]);
                            const int cb = __builtin_amdgcn_ds_bpermute(ad, (int)pk[2*kk+1][pr]);
                            pa.u[hp * 2 + pr] = (g8 < 2) ? (unsigned int)ca : (unsigned int)cb;
                        }
                    }
#pragma unroll
                    for (int dt = 0; dt < 8; ++dt) {
                        bf16x8 vb = *(const bf16x8*)(bV + (kk * 4 + g8) * 2048 + ((dt << 4) + l15) * 16);
                        oacc[dt] = __builtin_amdgcn_mfma_f32_16x16x32_bf16(pa.v, vb, oacc[dt], 0, 0, 0);
                    }
                }
                __builtin_amdgcn_s_setprio(0);
            }

            if (c + 1 < nch) write_buf((c + 1) & 1);
            if (c + 2 < nch) load_chunk((c + 2) << 6);
            __syncthreads();
        }

        // ---- write O (f32): row orow0+r, col dt*16+l15 ----
#pragma unroll
        for (int r = 0; r < 4; ++r) {
            const int gir = orow0 + r;
            if (gir < L) {
                float* op = Out + (size_t)(s0 + gir) * HD + h * 128 + l15;
#pragma unroll
                for (int dt = 0; dt < 8; ++dt) op[dt << 4] = oacc[dt][r];
            }
        }
    }
}

extern "C" void kernel_launch(void* const* d_in, const int* in_sizes, int n_in,
                              void* d_out, int out_size, void* d_ws, size_t ws_size,
                              hipStream_t stream) {
    (void)in_sizes; (void)n_in; (void)ws_size; (void)out_size;
    const float* q = (const float*)d_in[0];
    const float* k = (const float*)d_in[1];
    const float* v = (const float*)d_in[2];
    const int* offs = (const int*)d_in[3];
    const int* ntgt = (const int*)d_in[4];
    float* out = (float*)d_out;
    unsigned int* ctr = (unsigned int*)d_ws;
    hipMemsetAsync(ctr, 0, 4, stream);
    dim3 grid(512, 1, 1), block(512, 1, 1);
    hipLaunchKernelGGL(hstu_attn_fwd, grid, block, 0, stream, q, k, v, offs, ntgt, out, ctr);
}